// Round 16
// baseline (127.568 us; speedup 1.0000x reference)
//
#include <hip/hip_runtime.h>
#include <math.h>

// Problem constants
#define BATCH 262144

// ws layout (float offsets)
#define WA_OFF  0        // [48 frags][64 lanes][8 bf16] A-fragments of W^T (12288 floats)
#define G6_OFF  18944    // [8][8]  C^T diag(1/(R+1e-6)) C
#define G8_OFF  19008    // [8][8]  C^T diag(1/(R+1e-8)) C
#define R6_OFF  19072    // [16] 1/(R+1e-6)
#define R8_OFF  19088    // [16] 1/(R+1e-8)
#define SLR_OFF 19104    // scalar: sum log(R+1e-6)

typedef __attribute__((ext_vector_type(8))) short bf16x8;
typedef __attribute__((ext_vector_type(4))) float f32x4;

__device__ __forceinline__ float rcp1(float x) {
    float r = __builtin_amdgcn_rcpf(x);
    return r * (2.0f - x * r);   // Newton step: used in tail only
}
// lstm nonlinearity: raw v_rcp (rel err ~6e-5, invisible vs bf16 GEMM noise)
__device__ __forceinline__ float sigm(float x) {
    float e = __expf(-fabsf(x));
    float s = __builtin_amdgcn_rcpf(1.0f + e);
    return (x >= 0.0f) ? s : e * s;
}
__device__ __forceinline__ float tanh_f(float x) {
    float e = __expf(-2.0f * fabsf(x));
    float t = (1.0f - e) * __builtin_amdgcn_rcpf(1.0f + e);
    return copysignf(t, x);
}
__device__ __forceinline__ unsigned rne_bf16(float x) {
    unsigned u = __float_as_uint(x);
    return (u + 0x7fffu + ((u >> 16) & 1u)) >> 16;   // round-to-nearest-even bf16
}
__device__ __forceinline__ unsigned pack2(float lo, float hi) {
    return rne_bf16(lo) | (rne_bf16(hi) << 16);
}

// ---------------- prep: A-fragments (bf16) + batch-independent stats ---------
__global__ void prep_kernel(const float* __restrict__ Wk,   // [8][256]
                            const float* __restrict__ Wr,   // [64][256]
                            const float* __restrict__ Cm,   // [16][8]
                            const float* __restrict__ logR, // [16]
                            float* __restrict__ ws) {
    int b = blockIdx.x;
    int t = threadIdx.x;
    if (b < 12) {
        unsigned* wa = (unsigned*)(ws + WA_OFF);
        int F  = b * 256 + t;          // 0..3071 = frag(48) x lane(64)
        int fr = F >> 6, l = F & 63;
        int m  = fr / 3, ks = fr % 3;
        int c  = m * 16 + (l & 15);    // gate-interleaved col = u*4+g
        int k0 = ks * 32 + (l >> 4) * 8;
        int src = (c & 3) * 64 + (c >> 2);   // original col g*64+u
        float v[8];
#pragma unroll
        for (int j = 0; j < 8; ++j) {
            int k = k0 + j;
            v[j] = (k < 8) ? Wk[k * 256 + src] : (k < 72 ? Wr[(k - 8) * 256 + src] : 0.0f);
        }
        wa[F * 4 + 0] = pack2(v[0], v[1]);
        wa[F * 4 + 1] = pack2(v[2], v[3]);
        wa[F * 4 + 2] = pack2(v[4], v[5]);
        wa[F * 4 + 3] = pack2(v[6], v[7]);
        return;
    }
    if (t < 64) {
        int k = t >> 3, l = t & 7;
        float g6 = 0.0f, g8 = 0.0f;
        for (int i = 0; i < 16; ++i) {
            float R  = expf(logR[i]);
            float cc = Cm[i * 8 + k] * Cm[i * 8 + l];
            g6 += cc / (R + 1e-6f);
            g8 += cc / (R + 1e-8f);
        }
        ws[G6_OFF + t] = g6;
        ws[G8_OFF + t] = g8;
    } else if (t < 80) {
        int i = t - 64;
        float R = expf(logR[i]);
        ws[R6_OFF + i] = 1.0f / (R + 1e-6f);
        ws[R8_OFF + i] = 1.0f / (R + 1e-8f);
    } else if (t == 80) {
        float s = 0.0f;
        for (int i = 0; i < 16; ++i) s += logf(expf(logR[i]) + 1e-6f);
        ws[SLR_OFF] = s;
    }
}

// ---------------- LSTM kernel: MFMA bf16 GEMM + mu/lsg stash -----------------
// r14 structure, critical-path trimmed:
//  - c_old loads issued at kernel TOP (~1500cy before use -> HBM latency fully
//    hidden; GEMM-phase liveness unchanged vs r14, no spill).
//  - z staged DIRECTLY into frag buffer as bf16 (z[e][0..7] contiguous in
//    global; its chunks ks=0,hi=0 are disjoint from h's hi>=1) -> ha buffer is
//    h-only [e][68], conversion is a clean 2x256 loop.
// D layout (m89): lane's 4 acc regs = gates (i,f,g,o) of unit u=16w+4mm+(l>>4)
// for element e=n*16+(l&15). mu/lsg stashed in elem's V slot (r10 pattern).
__global__ __launch_bounds__(256)
void lstm_kernel(const float* __restrict__ h_in,
                 const float* __restrict__ c_in,
                 const float* __restrict__ z_prev,
                 const float* __restrict__ b_lstm,
                 const float* __restrict__ W_mu,
                 const float* __restrict__ b_mu,
                 const float* __restrict__ W_ls,
                 const float* __restrict__ b_ls,
                 const float* __restrict__ ws,
                 float* __restrict__ out) {
    __shared__ __align__(16) float r1[64 * 68];  // h fp32 [e][68]; -> cbuf [e][68]
    __shared__ __align__(16) float r2[64 * 68];  // B-frags (3072 words); -> hbuf [u][68]

    const int t   = threadIdx.x;
    const int l   = t & 63;
    const int wvu = __builtin_amdgcn_readfirstlane(t >> 6);
    const int lhi = l >> 4, llo = l & 15;
    const size_t E0 = (size_t)blockIdx.x * 64;
    unsigned* fr = (unsigned*)r2;

    // ---- issue c_old loads FIRST (latency hides under staging+conv+GEMM) ----
    float4 cp0 = *(const float4*)(c_in + E0 * 64 + 0 * 1024 + t * 4);
    float4 cp1 = *(const float4*)(c_in + E0 * 64 + 1 * 1024 + t * 4);
    float4 cp2 = *(const float4*)(c_in + E0 * 64 + 2 * 1024 + t * 4);
    float4 cp3 = *(const float4*)(c_in + E0 * 64 + 3 * 1024 + t * 4);

    // ---- stage h fp32 row-major ----
#pragma unroll
    for (int i = 0; i < 4; ++i) {
        int g = i * 1024 + t * 4;
        int e = g >> 6, u = g & 63;
        float4 hv = *(const float4*)(h_in + E0 * 64 + g);
        *(float4*)(r1 + e * 68 + u) = hv;
    }
    // ---- stage z directly as bf16 frags (k=0..7 -> ks=0, hi=0 chunks) ----
    if (t < 64) {
        float4 za = *(const float4*)(z_prev + (E0 + t) * 8);
        float4 zb = *(const float4*)(z_prev + (E0 + t) * 8 + 4);
        uint4 pk;
        pk.x = pack2(za.x, za.y);
        pk.y = pack2(za.z, za.w);
        pk.z = pack2(zb.x, zb.y);
        pk.w = pack2(zb.z, zb.w);
        int F = ((t >> 4) * 3) * 64 + (t & 15);   // n=e>>4, ks=0, hi=0, lo=e&15
        *(uint4*)(fr + F * 4) = pk;
    }
    // ---- zero-pad k = 72..95 (ks=2, hi=1..3) ----
    if (t >= 64 && t < 256) {
        int r = t - 64;                 // 0..191
        int n = r / 48, q = r % 48;
        int hi = q / 16 + 1, lo = q & 15;
        int F = (n * 3 + 2) * 64 + hi * 16 + lo;
        *(uint4*)(fr + F * 4) = make_uint4(0, 0, 0, 0);
    }
    __syncthreads();   // b1: h staged (z/pad frags also done)

    // ---- convert h -> bf16 B-fragments (k=8..71; 512 items = 2x256) ----
#pragma unroll
    for (int j = 0; j < 2; ++j) {
        int idx = j * 256 + t;
        int e = idx & 63, kc = idx >> 6;     // kc 0..7 -> k0 = 8 + kc*8
        int k0 = 8 + kc * 8;
        float4 va = *(const float4*)(r1 + e * 68 + k0 - 8);
        float4 vb = *(const float4*)(r1 + e * 68 + k0 - 4);
        uint4 pk;
        pk.x = pack2(va.x, va.y);
        pk.y = pack2(va.z, va.w);
        pk.z = pack2(vb.x, vb.y);
        pk.w = pack2(vb.z, vb.w);
        int n = e >> 4, lo = e & 15, ks = k0 >> 5, hi = (k0 & 31) >> 3;
        int F = (n * 3 + ks) * 64 + hi * 16 + lo;
        *(uint4*)(fr + F * 4) = pk;
    }
    __syncthreads();   // b2: frags ready; r1 (h) dead

    // ---- MFMA GEMM: 48 mfma/wave ----
    f32x4 acc[4][4];
#pragma unroll
    for (int mm = 0; mm < 4; ++mm)
#pragma unroll
        for (int n = 0; n < 4; ++n) acc[mm][n] = (f32x4){0.f, 0.f, 0.f, 0.f};

    const unsigned* WA = (const unsigned*)(ws + WA_OFF);
#pragma unroll
    for (int ks = 0; ks < 3; ++ks) {
        bf16x8 bfr[4], afr[4];
#pragma unroll
        for (int n = 0; n < 4; ++n)
            bfr[n] = *(const bf16x8*)(fr + ((n * 3 + ks) * 64 + l) * 4);
#pragma unroll
        for (int mm = 0; mm < 4; ++mm)
            afr[mm] = *(const bf16x8*)(WA + (((4 * wvu + mm) * 3 + ks) * 64 + l) * 4);
#pragma unroll
        for (int mm = 0; mm < 4; ++mm)
#pragma unroll
            for (int n = 0; n < 4; ++n)
                acc[mm][n] = __builtin_amdgcn_mfma_f32_16x16x32_bf16(
                    afr[mm], bfr[n], acc[mm][n], 0, 0, 0);
    }

    // ---- write cbuf [e][68] (r1 reuse; c loads issued at top) ----
    float* cbuf = r1;
    {
        int g0 = t * 4;
        *(float4*)(cbuf + ((g0 >> 6)) * 68 + (g0 & 63)) = cp0;
        int g1 = 1024 + t * 4;
        *(float4*)(cbuf + ((g1 >> 6)) * 68 + (g1 & 63)) = cp1;
        int g2 = 2048 + t * 4;
        *(float4*)(cbuf + ((g2 >> 6)) * 68 + (g2 & 63)) = cp2;
        int g3 = 3072 + t * 4;
        *(float4*)(cbuf + ((g3 >> 6)) * 68 + (g3 & 63)) = cp3;
    }
    __syncthreads();   // b3: cbuf staged + all frag reads done

    // ---- nonlinearity: lane owns 4u x 4e x 4 gates ----
    float* hbuf = r2;   // [u][68]
#pragma unroll
    for (int mm = 0; mm < 4; ++mm) {
        int u = 16 * wvu + 4 * mm + lhi;
        float bi = b_lstm[u], bf_ = b_lstm[64 + u], bg = b_lstm[128 + u], bo = b_lstm[192 + u];
#pragma unroll
        for (int n = 0; n < 4; ++n) {
            int e = n * 16 + llo;
            float zi = acc[mm][n][0] + bi;
            float zf = acc[mm][n][1] + bf_;
            float zg = acc[mm][n][2] + bg;
            float zo = acc[mm][n][3] + bo;
            float cold = cbuf[e * 68 + u];
            float cn = sigm(zf) * cold + sigm(zi) * tanh_f(zg);
            float hn = sigm(zo) * tanh_f(cn);
            cbuf[e * 68 + u] = cn;        // own slot
            hbuf[u * 68 + e] = hn;
        }
    }
    __syncthreads();   // b4: hbuf/cbuf final

    // ---- coalesced write-out of h_new / c_new ----
    float* outH = out + (size_t)BATCH * 73  + E0 * 64;
    float* outC = out + (size_t)BATCH * 137 + E0 * 64;
#pragma unroll
    for (int i = 0; i < 4; ++i) {
        int g = i * 1024 + t * 4;
        int e = g >> 6, u = g & 63;
        *(float4*)(outC + g) = *(const float4*)(cbuf + e * 68 + u);
        float4 hv = make_float4(hbuf[(u + 0) * 68 + e], hbuf[(u + 1) * 68 + e],
                                hbuf[(u + 2) * 68 + e], hbuf[(u + 3) * 68 + e]);
        *(float4*)(outH + g) = hv;
    }

    // ---- mu/log_sigma: wave wvu computes outputs 4wvu..4wvu+3 for elem l ----
    {
        const float* Wsel = (wvu < 2) ? W_mu : W_ls;
        const float* bsel = (wvu < 2) ? b_mu : b_ls;
        const int d0 = (wvu & 1) * 4;
        float m0 = bsel[d0 + 0], m1 = bsel[d0 + 1], m2 = bsel[d0 + 2], m3 = bsel[d0 + 3];
#pragma unroll
        for (int u = 0; u < 64; ++u) {
            float hv = hbuf[u * 68 + l];
            m0 = fmaf(hv, Wsel[u * 8 + d0 + 0], m0);
            m1 = fmaf(hv, Wsel[u * 8 + d0 + 1], m1);
            m2 = fmaf(hv, Wsel[u * 8 + d0 + 2], m2);
            m3 = fmaf(hv, Wsel[u * 8 + d0 + 3], m3);
        }
        float* slot = out + (size_t)BATCH * 9 + (E0 + l) * 64 + wvu * 4;
        *(float4*)slot = make_float4(m0, m1, m2, m3);
    }
}

// ---------------- tail kernel: Gaussian tail from stashed mu/lsg -------------
__global__ __launch_bounds__(256)
void tail_kernel(const float* __restrict__ x_in,
                 const float* __restrict__ Cm,
                 const float* __restrict__ b_em,
                 const float* __restrict__ ws,
                 float* __restrict__ out) {
    __shared__ float vbuf[64 * 65];   // V staging per 64-elem chunk

    const int t    = threadIdx.x;
    const int lane = t & 63;
    const int wv   = t >> 6;
    const int blk  = blockIdx.x;
    const size_t e = (size_t)blk * 256 + t;

    const float* G6 = ws + G6_OFF;
    const float* G8 = ws + G8_OFF;
    const float* r6 = ws + R6_OFF;
    const float* r8 = ws + R8_OFF;
    const float  slr = ws[SLR_OFF];

    // ---- independent x load issued FIRST; stash reads follow ----
    float4 xq0 = *(const float4*)(x_in + e * 16 + 0);
    float4 xq1 = *(const float4*)(x_in + e * 16 + 4);
    float4 xq2 = *(const float4*)(x_in + e * 16 + 8);
    float4 xq3 = *(const float4*)(x_in + e * 16 + 12);

    const float* tmp = out + (size_t)BATCH * 9 + e * 64;
    float4 q0 = *(const float4*)(tmp + 0);
    float4 q1 = *(const float4*)(tmp + 4);
    float4 q2 = *(const float4*)(tmp + 8);
    float4 q3 = *(const float4*)(tmp + 12);
    float mu[8]  = {q0.x, q0.y, q0.z, q0.w, q1.x, q1.y, q1.z, q1.w};
    float lsg[8] = {q2.x, q2.y, q2.z, q2.w, q3.x, q3.y, q3.z, q3.w};
    float xv[16] = {xq0.x, xq0.y, xq0.z, xq0.w, xq1.x, xq1.y, xq1.z, xq1.w,
                    xq2.x, xq2.y, xq2.z, xq2.w, xq3.x, xq3.y, xq3.z, xq3.w};

    float sig[8], Sinv[8];
#pragma unroll
    for (int d = 0; d < 8; ++d) {
        float l = fminf(fmaxf(lsg[d], -5.0f), 3.0f);
        float s = __expf(l);
        sig[d]  = s;
        Sinv[d] = rcp1(s * s + 1e-8f);
    }

    float t6[8], t8[8];
#pragma unroll
    for (int k = 0; k < 8; ++k) { t6[k] = 0.0f; t8[k] = 0.0f; }
    float qdr = 0.0f;
#pragma unroll
    for (int i = 0; i < 16; ++i) {
        float pm = b_em[i];
#pragma unroll
        for (int d = 0; d < 8; ++d) pm = fmaf(mu[d], Cm[i * 8 + d], pm);
        float df = xv[i] - pm;
        float xe = xv[i] - b_em[i];
        float a6 = df * r6[i];
        float a8 = xe * r8[i];
        qdr = fmaf(df, a6, qdr);
#pragma unroll
        for (int k = 0; k < 8; ++k) {
            t6[k] = fmaf(a6, Cm[i * 8 + k], t6[k]);
            t8[k] = fmaf(a8, Cm[i * 8 + k], t8[k]);
        }
    }

    // ---- alpha via Woodbury ----
    float M[8][8];
#pragma unroll
    for (int k = 0; k < 8; ++k)
#pragma unroll
        for (int l = 0; l <= k; ++l)
            M[k][l] = ((k == l) ? 1.0f : 0.0f) + sig[k] * sig[l] * G6[k * 8 + l];

    float ldia[8];
    float logdetM = 0.0f;
#pragma unroll
    for (int k = 0; k < 8; ++k) {
        float d = M[k][k];
#pragma unroll
        for (int j = 0; j < k; ++j) d = fmaf(-M[k][j], M[k][j], d);
        float l = sqrtf(d);
        logdetM += __logf(d);
        float li = rcp1(l);
        M[k][k] = l; ldia[k] = li;
#pragma unroll
        for (int i = k + 1; i < 8; ++i) {
            float s = M[i][k];
#pragma unroll
            for (int j = 0; j < k; ++j) s = fmaf(-M[i][j], M[k][j], s);
            M[i][k] = s * li;
        }
    }
    float w[8];
    float ssq = 0.0f;
#pragma unroll
    for (int k = 0; k < 8; ++k) {
        float s = sig[k] * t6[k];
#pragma unroll
        for (int j = 0; j < k; ++j) s = fmaf(-M[k][j], w[j], s);
        w[k] = s * ldia[k];
        ssq  = fmaf(w[k], w[k], ssq);
    }
    float mahal  = qdr - ssq;
    float alpha  = -0.5f * (mahal + slr + logdetM + 29.40603306254952f); // 16*ln(2pi)

    // ---- gamma: V = (diag(Sinv)+1e-6 I + G8)^-1 ----
    float Vi[8][8];
#pragma unroll
    for (int k = 0; k < 8; ++k)
#pragma unroll
        for (int l = 0; l <= k; ++l)
            Vi[k][l] = G8[k * 8 + l] + ((k == l) ? (Sinv[k] + 1e-6f) : 0.0f);

    float vdia[8];
#pragma unroll
    for (int k = 0; k < 8; ++k) {
        float d = Vi[k][k];
#pragma unroll
        for (int j = 0; j < k; ++j) d = fmaf(-Vi[k][j], Vi[k][j], d);
        float l = sqrtf(d);
        float li = rcp1(l);
        Vi[k][k] = l; vdia[k] = li;
#pragma unroll
        for (int i = k + 1; i < 8; ++i) {
            float s = Vi[i][k];
#pragma unroll
            for (int j = 0; j < k; ++j) s = fmaf(-Vi[i][j], Vi[k][j], s);
            Vi[i][k] = s * li;
        }
    }
    // J = L^-1 (lower), stored into M (dead)
#pragma unroll
    for (int k = 0; k < 8; ++k) {
        M[k][k] = vdia[k];
#pragma unroll
        for (int i = k + 1; i < 8; ++i) {
            float s = 0.0f;
#pragma unroll
            for (int j = k; j < i; ++j) s = fmaf(Vi[i][j], M[j][k], s);
            M[i][k] = -s * vdia[i];
        }
    }
    float info[8];
#pragma unroll
    for (int k = 0; k < 8; ++k) info[k] = fmaf(Sinv[k], mu[k], t8[k]);

    // ---- V = J^T J + gamma, staged through LDS in 4 chunks ----
    // First __syncthreads drains vmcnt for all threads -> every thread's
    // stash loads completed before any V store. Race-free overwrite.
#pragma unroll 1
    for (int ch = 0; ch < 4; ++ch) {
        if (wv == ch) {
            float gam[8];
#pragma unroll
            for (int a = 0; a < 8; ++a) gam[a] = 0.0f;
#pragma unroll
            for (int a = 0; a < 8; ++a) {
#pragma unroll
                for (int b = 0; b < 8; ++b) {
                    int m0 = (a > b) ? a : b;
                    float s = 0.0f;
#pragma unroll
                    for (int i = 0; i < 8; ++i)
                        if (i >= m0) s = fmaf(M[i][a], M[i][b], s);
                    vbuf[(a * 8 + b) * 65 + lane] = s;
                    gam[a] = fmaf(s, info[b], gam[a]);
                }
            }
            out[e] = alpha;
            float4* outG = (float4*)(out + (size_t)BATCH + e * 8);
            outG[0] = make_float4(gam[0], gam[1], gam[2], gam[3]);
            outG[1] = make_float4(gam[4], gam[5], gam[6], gam[7]);
        }
        __syncthreads();
        {
            float* outV = out + (size_t)BATCH * 9 + ((size_t)blk * 256 + (size_t)ch * 64) * 64;
#pragma unroll
            for (int i = 0; i < 4; ++i) {
                int g = i * 1024 + t * 4;
                int ee = g >> 6, j = g & 63;
                float4 v = make_float4(vbuf[(j + 0) * 65 + ee], vbuf[(j + 1) * 65 + ee],
                                       vbuf[(j + 2) * 65 + ee], vbuf[(j + 3) * 65 + ee]);
                *(float4*)(outV + g) = v;
            }
        }
        __syncthreads();
    }
}

extern "C" void kernel_launch(void* const* d_in, const int* in_sizes, int n_in,
                              void* d_out, int out_size, void* d_ws, size_t ws_size,
                              hipStream_t stream) {
    const float* h    = (const float*)d_in[0];
    const float* c    = (const float*)d_in[1];
    const float* zp   = (const float*)d_in[2];
    const float* xt   = (const float*)d_in[3];
    const float* Wk   = (const float*)d_in[4];
    const float* Wr   = (const float*)d_in[5];
    const float* bl   = (const float*)d_in[6];
    const float* Wmu  = (const float*)d_in[7];
    const float* bmu  = (const float*)d_in[8];
    const float* Wls  = (const float*)d_in[9];
    const float* bls  = (const float*)d_in[10];
    const float* Cm   = (const float*)d_in[11];
    const float* bem  = (const float*)d_in[12];
    const float* logR = (const float*)d_in[13];
    float* ws  = (float*)d_ws;
    float* out = (float*)d_out;

    hipLaunchKernelGGL(prep_kernel, dim3(13), dim3(256), 0, stream, Wk, Wr, Cm, logR, ws);
    hipLaunchKernelGGL(lstm_kernel, dim3(BATCH / 64), dim3(256), 0, stream,
                       h, c, zp, bl, Wmu, bmu, Wls, bls, ws, out);
    hipLaunchKernelGGL(tail_kernel, dim3(BATCH / 256), dim3(256), 0, stream,
                       xt, Cm, bem, ws, out);
}

// Round 17
// 111.276 us; speedup vs baseline: 1.1464x; 1.1464x over previous
//
#include <hip/hip_runtime.h>
#include <math.h>

// Problem constants
#define BATCH 262144

// ws layout (float offsets)
#define WA_OFF  0        // [48 frags][64 lanes][8 bf16] A-fragments of W^T (12288 floats)
#define G6_OFF  18944    // [8][8]  C^T diag(1/(R+1e-6)) C
#define G8_OFF  19008    // [8][8]  C^T diag(1/(R+1e-8)) C
#define R6_OFF  19072    // [16] 1/(R+1e-6)
#define R8_OFF  19088    // [16] 1/(R+1e-8)
#define SLR_OFF 19104    // scalar: sum log(R+1e-6)

typedef __attribute__((ext_vector_type(8))) short bf16x8;
typedef __attribute__((ext_vector_type(4))) float f32x4;

__device__ __forceinline__ float rcp1(float x) {
    float r = __builtin_amdgcn_rcpf(x);
    return r * (2.0f - x * r);   // Newton step: used in tail only
}
// lstm nonlinearity: raw v_rcp (rel err ~6e-5, invisible vs bf16 GEMM noise)
__device__ __forceinline__ float sigm(float x) {
    float e = __expf(-fabsf(x));
    float s = __builtin_amdgcn_rcpf(1.0f + e);
    return (x >= 0.0f) ? s : e * s;
}
__device__ __forceinline__ float tanh_f(float x) {
    float e = __expf(-2.0f * fabsf(x));
    float t = (1.0f - e) * __builtin_amdgcn_rcpf(1.0f + e);
    return copysignf(t, x);
}
__device__ __forceinline__ unsigned rne_bf16(float x) {
    unsigned u = __float_as_uint(x);
    return (u + 0x7fffu + ((u >> 16) & 1u)) >> 16;   // round-to-nearest-even bf16
}
__device__ __forceinline__ unsigned pack2(float lo, float hi) {
    return rne_bf16(lo) | (rne_bf16(hi) << 16);
}

// ---------------- prep: A-fragments (bf16) + batch-independent stats ---------
__global__ void prep_kernel(const float* __restrict__ Wk,   // [8][256]
                            const float* __restrict__ Wr,   // [64][256]
                            const float* __restrict__ Cm,   // [16][8]
                            const float* __restrict__ logR, // [16]
                            float* __restrict__ ws) {
    int b = blockIdx.x;
    int t = threadIdx.x;
    if (b < 12) {
        unsigned* wa = (unsigned*)(ws + WA_OFF);
        int F  = b * 256 + t;          // 0..3071 = frag(48) x lane(64)
        int fr = F >> 6, l = F & 63;
        int m  = fr / 3, ks = fr % 3;
        int c  = m * 16 + (l & 15);    // gate-interleaved col = u*4+g
        int k0 = ks * 32 + (l >> 4) * 8;
        int src = (c & 3) * 64 + (c >> 2);   // original col g*64+u
        float v[8];
#pragma unroll
        for (int j = 0; j < 8; ++j) {
            int k = k0 + j;
            v[j] = (k < 8) ? Wk[k * 256 + src] : (k < 72 ? Wr[(k - 8) * 256 + src] : 0.0f);
        }
        wa[F * 4 + 0] = pack2(v[0], v[1]);
        wa[F * 4 + 1] = pack2(v[2], v[3]);
        wa[F * 4 + 2] = pack2(v[4], v[5]);
        wa[F * 4 + 3] = pack2(v[6], v[7]);
        return;
    }
    // block 12: batch-independent stats
    if (t < 64) {
        int k = t >> 3, l = t & 7;
        float g6 = 0.0f, g8 = 0.0f;
        for (int i = 0; i < 16; ++i) {
            float R  = expf(logR[i]);
            float cc = Cm[i * 8 + k] * Cm[i * 8 + l];
            g6 += cc / (R + 1e-6f);
            g8 += cc / (R + 1e-8f);
        }
        ws[G6_OFF + t] = g6;
        ws[G8_OFF + t] = g8;
    } else if (t < 80) {
        int i = t - 64;
        float R = expf(logR[i]);
        ws[R6_OFF + i] = 1.0f / (R + 1e-6f);
        ws[R8_OFF + i] = 1.0f / (R + 1e-8f);
    } else if (t == 80) {
        float s = 0.0f;
        for (int i = 0; i < 16; ++i) s += logf(expf(logR[i]) + 1e-6f);
        ws[SLR_OFF] = s;
    }
}

// ---------------- LSTM kernel: MFMA bf16 GEMM + mu/lsg stash -----------------
// Block = 256 thr = 4 waves, 64 elements. D[c][e] = W^T ha^T: M=256 N=64 K=96.
// Wave w: M-tiles 4w..4w+3. 48 mfma_f32_16x16x32_bf16/wave. D layout (m89):
// lane's 4 acc regs = the 4 gates (i,f,g,o) of unit u=16w+4mm+(l>>4) for
// element e=n*16+(l&15). After nonlinearity, mu/log_sigma are computed from
// LDS h_new and stashed in out[B*9 + e*64 + 0..15] (element e's own V slot;
// tail reads then overwrites it -> race-free).
// NOTE r15 lesson: c_old loads must be issued AFTER the staging/conversion
// barriers (vmcnt is ordered -- older outstanding loads would serialize the
// staging waits). Issued just before the GEMM, used after b3: fully hidden.
__global__ __launch_bounds__(256)
void lstm_kernel(const float* __restrict__ h_in,
                 const float* __restrict__ c_in,
                 const float* __restrict__ z_prev,
                 const float* __restrict__ b_lstm,
                 const float* __restrict__ W_mu,
                 const float* __restrict__ b_mu,
                 const float* __restrict__ W_ls,
                 const float* __restrict__ b_ls,
                 const float* __restrict__ ws,
                 float* __restrict__ out) {
    __shared__ __align__(16) float r1[64 * 72];  // ha fp32 [e][72]; -> cbuf [e][68]
    __shared__ __align__(16) float r2[64 * 68];  // B-frags (3072 floats); -> hbuf [u][68]

    const int t   = threadIdx.x;
    const int l   = t & 63;
    const int wvu = __builtin_amdgcn_readfirstlane(t >> 6);
    const int lhi = l >> 4, llo = l & 15;
    const size_t E0 = (size_t)blockIdx.x * 64;

    // ---- stage ha fp32 row-major (coalesced, linear LDS writes) ----
#pragma unroll
    for (int i = 0; i < 4; ++i) {
        int g = i * 1024 + t * 4;
        int e = g >> 6, u = g & 63;
        float4 hv = *(const float4*)(h_in + E0 * 64 + g);
        *(float4*)(r1 + e * 72 + 8 + u) = hv;
    }
    if (t < 128) {
        int g = t * 4;
        int e = g >> 3, p = g & 7;
        float4 zv = *(const float4*)(z_prev + E0 * 8 + g);
        *(float4*)(r1 + e * 72 + p) = zv;
    }
    __syncthreads();   // b1: ha staged

    // ---- convert ha -> bf16 B-fragments ----
    unsigned* fr = (unsigned*)r2;
#pragma unroll
    for (int i = 0; i < 3; ++i) {
        int c = i * 256 + t;
        if (c < 576) {                       // 576 chunks of 8 floats (k<72)
            int e = c / 9, k0 = (c % 9) * 8;
            float4 va = *(const float4*)(r1 + c * 8);
            float4 vb = *(const float4*)(r1 + c * 8 + 4);
            uint4 pk;
            pk.x = pack2(va.x, va.y);
            pk.y = pack2(va.z, va.w);
            pk.z = pack2(vb.x, vb.y);
            pk.w = pack2(vb.z, vb.w);
            int n = e >> 4, lo = e & 15, ks = k0 >> 5, hi = (k0 & 31) >> 3;
            int F = (n * 3 + ks) * 64 + hi * 16 + lo;
            *(uint4*)(fr + F * 4) = pk;
        }
    }
    if (t < 192) {                           // zero-pad k = 72..95
        int n = t / 48, r = t % 48;
        int hi = r / 16 + 1, lo = r & 15;
        int F = (n * 3 + 2) * 64 + hi * 16 + lo;
        *(uint4*)(fr + F * 4) = make_uint4(0, 0, 0, 0);
    }
    __syncthreads();   // b2: frags ready; r1 (ha) dead

    // ---- issue c_old loads (latency hides under GEMM) ----
    float4 cp0 = *(const float4*)(c_in + E0 * 64 + 0 * 1024 + t * 4);
    float4 cp1 = *(const float4*)(c_in + E0 * 64 + 1 * 1024 + t * 4);
    float4 cp2 = *(const float4*)(c_in + E0 * 64 + 2 * 1024 + t * 4);
    float4 cp3 = *(const float4*)(c_in + E0 * 64 + 3 * 1024 + t * 4);

    // ---- MFMA GEMM: 48 mfma/wave ----
    f32x4 acc[4][4];
#pragma unroll
    for (int mm = 0; mm < 4; ++mm)
#pragma unroll
        for (int n = 0; n < 4; ++n) acc[mm][n] = (f32x4){0.f, 0.f, 0.f, 0.f};

    const unsigned* WA = (const unsigned*)(ws + WA_OFF);
#pragma unroll
    for (int ks = 0; ks < 3; ++ks) {
        bf16x8 bfr[4], afr[4];
#pragma unroll
        for (int n = 0; n < 4; ++n)
            bfr[n] = *(const bf16x8*)(fr + ((n * 3 + ks) * 64 + l) * 4);
#pragma unroll
        for (int mm = 0; mm < 4; ++mm)
            afr[mm] = *(const bf16x8*)(WA + (((4 * wvu + mm) * 3 + ks) * 64 + l) * 4);
#pragma unroll
        for (int mm = 0; mm < 4; ++mm)
#pragma unroll
            for (int n = 0; n < 4; ++n)
                acc[mm][n] = __builtin_amdgcn_mfma_f32_16x16x32_bf16(
                    afr[mm], bfr[n], acc[mm][n], 0, 0, 0);
    }

    // ---- write cbuf [e][68] (r1 reuse) ----
    float* cbuf = r1;
    {
        int g0 = t * 4;
        *(float4*)(cbuf + ((g0 >> 6)) * 68 + (g0 & 63)) = cp0;
        int g1 = 1024 + t * 4;
        *(float4*)(cbuf + ((g1 >> 6)) * 68 + (g1 & 63)) = cp1;
        int g2 = 2048 + t * 4;
        *(float4*)(cbuf + ((g2 >> 6)) * 68 + (g2 & 63)) = cp2;
        int g3 = 3072 + t * 4;
        *(float4*)(cbuf + ((g3 >> 6)) * 68 + (g3 & 63)) = cp3;
    }
    __syncthreads();   // b3: cbuf staged + all frag reads done

    // ---- nonlinearity: lane owns 4u x 4e x 4 gates ----
    float* hbuf = r2;   // [u][68]
#pragma unroll
    for (int mm = 0; mm < 4; ++mm) {
        int u = 16 * wvu + 4 * mm + lhi;
        float bi = b_lstm[u], bf_ = b_lstm[64 + u], bg = b_lstm[128 + u], bo = b_lstm[192 + u];
#pragma unroll
        for (int n = 0; n < 4; ++n) {
            int e = n * 16 + llo;
            float zi = acc[mm][n][0] + bi;
            float zf = acc[mm][n][1] + bf_;
            float zg = acc[mm][n][2] + bg;
            float zo = acc[mm][n][3] + bo;
            float cold = cbuf[e * 68 + u];
            float cn = sigm(zf) * cold + sigm(zi) * tanh_f(zg);
            float hn = sigm(zo) * tanh_f(cn);
            cbuf[e * 68 + u] = cn;        // own slot
            hbuf[u * 68 + e] = hn;
        }
    }
    __syncthreads();   // b4: hbuf/cbuf final

    // ---- coalesced write-out of h_new / c_new ----
    float* outH = out + (size_t)BATCH * 73  + E0 * 64;
    float* outC = out + (size_t)BATCH * 137 + E0 * 64;
#pragma unroll
    for (int i = 0; i < 4; ++i) {
        int g = i * 1024 + t * 4;
        int e = g >> 6, u = g & 63;
        *(float4*)(outC + g) = *(const float4*)(cbuf + e * 68 + u);
        float4 hv = make_float4(hbuf[(u + 0) * 68 + e], hbuf[(u + 1) * 68 + e],
                                hbuf[(u + 2) * 68 + e], hbuf[(u + 3) * 68 + e]);
        *(float4*)(outH + g) = hv;
    }

    // ---- mu/log_sigma: wave wvu computes outputs 4wvu..4wvu+3 for elem l ----
    // outputs 0-7 = mu (W_mu), 8-15 = lsg (W_ls); stash in elem's V slot.
    {
        const float* Wsel = (wvu < 2) ? W_mu : W_ls;
        const float* bsel = (wvu < 2) ? b_mu : b_ls;
        const int d0 = (wvu & 1) * 4;
        float m0 = bsel[d0 + 0], m1 = bsel[d0 + 1], m2 = bsel[d0 + 2], m3 = bsel[d0 + 3];
#pragma unroll
        for (int u = 0; u < 64; ++u) {
            float hv = hbuf[u * 68 + l];
            m0 = fmaf(hv, Wsel[u * 8 + d0 + 0], m0);
            m1 = fmaf(hv, Wsel[u * 8 + d0 + 1], m1);
            m2 = fmaf(hv, Wsel[u * 8 + d0 + 2], m2);
            m3 = fmaf(hv, Wsel[u * 8 + d0 + 3], m3);
        }
        float* slot = out + (size_t)BATCH * 9 + (E0 + l) * 64 + wvu * 4;
        *(float4*)slot = make_float4(m0, m1, m2, m3);
    }
}

// ---------------- tail kernel: Gaussian tail from stashed mu/lsg -------------
__global__ __launch_bounds__(256)
void tail_kernel(const float* __restrict__ x_in,
                 const float* __restrict__ Cm,
                 const float* __restrict__ b_em,
                 const float* __restrict__ ws,
                 float* __restrict__ out) {
    __shared__ float vbuf[64 * 65];   // V staging per 64-elem chunk

    const int t    = threadIdx.x;
    const int lane = t & 63;
    const int wv   = t >> 6;
    const int blk  = blockIdx.x;
    const size_t e = (size_t)blk * 256 + t;

    const float* G6 = ws + G6_OFF;
    const float* G8 = ws + G8_OFF;
    const float* r6 = ws + R6_OFF;
    const float* r8 = ws + R8_OFF;
    const float  slr = ws[SLR_OFF];

    // ---- read stashed mu/lsg from this element's V slot ----
    const float* tmp = out + (size_t)BATCH * 9 + e * 64;
    float4 q0 = *(const float4*)(tmp + 0);
    float4 q1 = *(const float4*)(tmp + 4);
    float4 q2 = *(const float4*)(tmp + 8);
    float4 q3 = *(const float4*)(tmp + 12);
    float mu[8]  = {q0.x, q0.y, q0.z, q0.w, q1.x, q1.y, q1.z, q1.w};
    float lsg[8] = {q2.x, q2.y, q2.z, q2.w, q3.x, q3.y, q3.z, q3.w};

    float sig[8], Sinv[8];
#pragma unroll
    for (int d = 0; d < 8; ++d) {
        float l = fminf(fmaxf(lsg[d], -5.0f), 3.0f);
        float s = __expf(l);
        sig[d]  = s;
        Sinv[d] = rcp1(s * s + 1e-8f);
    }

    float xv[16];
    {
        const float4* x4 = (const float4*)(x_in + e * 16);
#pragma unroll
        for (int q = 0; q < 4; ++q) {
            float4 v = x4[q];
            xv[4 * q + 0] = v.x; xv[4 * q + 1] = v.y;
            xv[4 * q + 2] = v.z; xv[4 * q + 3] = v.w;
        }
    }

    float t6[8], t8[8];
#pragma unroll
    for (int k = 0; k < 8; ++k) { t6[k] = 0.0f; t8[k] = 0.0f; }
    float qdr = 0.0f;
#pragma unroll
    for (int i = 0; i < 16; ++i) {
        float pm = b_em[i];
#pragma unroll
        for (int d = 0; d < 8; ++d) pm = fmaf(mu[d], Cm[i * 8 + d], pm);
        float df = xv[i] - pm;
        float xe = xv[i] - b_em[i];
        float a6 = df * r6[i];
        float a8 = xe * r8[i];
        qdr = fmaf(df, a6, qdr);
#pragma unroll
        for (int k = 0; k < 8; ++k) {
            t6[k] = fmaf(a6, Cm[i * 8 + k], t6[k]);
            t8[k] = fmaf(a8, Cm[i * 8 + k], t8[k]);
        }
    }

    // ---- alpha via Woodbury ----
    float M[8][8];
#pragma unroll
    for (int k = 0; k < 8; ++k)
#pragma unroll
        for (int l = 0; l <= k; ++l)
            M[k][l] = ((k == l) ? 1.0f : 0.0f) + sig[k] * sig[l] * G6[k * 8 + l];

    float ldia[8];
    float logdetM = 0.0f;
#pragma unroll
    for (int k = 0; k < 8; ++k) {
        float d = M[k][k];
#pragma unroll
        for (int j = 0; j < k; ++j) d = fmaf(-M[k][j], M[k][j], d);
        float l = sqrtf(d);
        logdetM += __logf(d);
        float li = rcp1(l);
        M[k][k] = l; ldia[k] = li;
#pragma unroll
        for (int i = k + 1; i < 8; ++i) {
            float s = M[i][k];
#pragma unroll
            for (int j = 0; j < k; ++j) s = fmaf(-M[i][j], M[k][j], s);
            M[i][k] = s * li;
        }
    }
    float w[8];
    float ssq = 0.0f;
#pragma unroll
    for (int k = 0; k < 8; ++k) {
        float s = sig[k] * t6[k];
#pragma unroll
        for (int j = 0; j < k; ++j) s = fmaf(-M[k][j], w[j], s);
        w[k] = s * ldia[k];
        ssq  = fmaf(w[k], w[k], ssq);
    }
    float mahal  = qdr - ssq;
    float alpha  = -0.5f * (mahal + slr + logdetM + 29.40603306254952f); // 16*ln(2pi)

    // ---- gamma: V = (diag(Sinv)+1e-6 I + G8)^-1 ----
    float Vi[8][8];
#pragma unroll
    for (int k = 0; k < 8; ++k)
#pragma unroll
        for (int l = 0; l <= k; ++l)
            Vi[k][l] = G8[k * 8 + l] + ((k == l) ? (Sinv[k] + 1e-6f) : 0.0f);

    float vdia[8];
#pragma unroll
    for (int k = 0; k < 8; ++k) {
        float d = Vi[k][k];
#pragma unroll
        for (int j = 0; j < k; ++j) d = fmaf(-Vi[k][j], Vi[k][j], d);
        float l = sqrtf(d);
        float li = rcp1(l);
        Vi[k][k] = l; vdia[k] = li;
#pragma unroll
        for (int i = k + 1; i < 8; ++i) {
            float s = Vi[i][k];
#pragma unroll
            for (int j = 0; j < k; ++j) s = fmaf(-Vi[i][j], Vi[k][j], s);
            Vi[i][k] = s * li;
        }
    }
    // J = L^-1 (lower), stored into M (dead)
#pragma unroll
    for (int k = 0; k < 8; ++k) {
        M[k][k] = vdia[k];
#pragma unroll
        for (int i = k + 1; i < 8; ++i) {
            float s = 0.0f;
#pragma unroll
            for (int j = k; j < i; ++j) s = fmaf(Vi[i][j], M[j][k], s);
            M[i][k] = -s * vdia[i];
        }
    }
    float info[8];
#pragma unroll
    for (int k = 0; k < 8; ++k) info[k] = fmaf(Sinv[k], mu[k], t8[k]);

    // ---- V = J^T J + gamma, staged through LDS in 4 chunks ----
    // First __syncthreads drains vmcnt for all threads -> every thread's
    // stash loads completed before any V store. Race-free overwrite.
#pragma unroll 1
    for (int ch = 0; ch < 4; ++ch) {
        if (wv == ch) {
            float gam[8];
#pragma unroll
            for (int a = 0; a < 8; ++a) gam[a] = 0.0f;
#pragma unroll
            for (int a = 0; a < 8; ++a) {
#pragma unroll
                for (int b = 0; b < 8; ++b) {
                    int m0 = (a > b) ? a : b;
                    float s = 0.0f;
#pragma unroll
                    for (int i = 0; i < 8; ++i)
                        if (i >= m0) s = fmaf(M[i][a], M[i][b], s);
                    vbuf[(a * 8 + b) * 65 + lane] = s;
                    gam[a] = fmaf(s, info[b], gam[a]);
                }
            }
            out[e] = alpha;
            float4* outG = (float4*)(out + (size_t)BATCH + e * 8);
            outG[0] = make_float4(gam[0], gam[1], gam[2], gam[3]);
            outG[1] = make_float4(gam[4], gam[5], gam[6], gam[7]);
        }
        __syncthreads();
        {
            float* outV = out + (size_t)BATCH * 9 + ((size_t)blk * 256 + (size_t)ch * 64) * 64;
#pragma unroll
            for (int i = 0; i < 4; ++i) {
                int g = i * 1024 + t * 4;
                int ee = g >> 6, j = g & 63;
                float4 v = make_float4(vbuf[(j + 0) * 65 + ee], vbuf[(j + 1) * 65 + ee],
                                       vbuf[(j + 2) * 65 + ee], vbuf[(j + 3) * 65 + ee]);
                *(float4*)(outV + g) = v;
            }
        }
        __syncthreads();
    }
}

extern "C" void kernel_launch(void* const* d_in, const int* in_sizes, int n_in,
                              void* d_out, int out_size, void* d_ws, size_t ws_size,
                              hipStream_t stream) {
    const float* h    = (const float*)d_in[0];
    const float* c    = (const float*)d_in[1];
    const float* zp   = (const float*)d_in[2];
    const float* xt   = (const float*)d_in[3];
    const float* Wk   = (const float*)d_in[4];
    const float* Wr   = (const float*)d_in[5];
    const float* bl   = (const float*)d_in[6];
    const float* Wmu  = (const float*)d_in[7];
    const float* bmu  = (const float*)d_in[8];
    const float* Wls  = (const float*)d_in[9];
    const float* bls  = (const float*)d_in[10];
    const float* Cm   = (const float*)d_in[11];
    const float* bem  = (const float*)d_in[12];
    const float* logR = (const float*)d_in[13];
    float* ws  = (float*)d_ws;
    float* out = (float*)d_out;

    hipLaunchKernelGGL(prep_kernel, dim3(13), dim3(256), 0, stream, Wk, Wr, Cm, logR, ws);
    hipLaunchKernelGGL(lstm_kernel, dim3(BATCH / 64), dim3(256), 0, stream,
                       h, c, zp, bl, Wmu, bmu, Wls, bls, ws, out);
    hipLaunchKernelGGL(tail_kernel, dim3(BATCH / 256), dim3(256), 0, stream,
                       xt, Cm, bem, ws, out);
}